// Round 1
// baseline (1664.886 us; speedup 1.0000x reference)
//
#include <hip/hip_runtime.h>

#define NPTS 2048
#define BATCH 4
#define CFEAT 64
#define MCENT 512

// ---------------- weight packing ----------------
// ws layout (floats): [0, 6144) cent as [b][m][3]; [6144, 6144+76800) packed weights.
// Segments (offset, cout, cin, kp):
// s0l0 @0      64x67  kp68
// s0l1 @4352   64x64  kp68
// s0l2 @8704   128x64 kp68
// s1l0 @17408  128x67 kp68
// s1l1 @26112  128x128 kp132
// s1l2 @43008  256x128 kp132   -> end 76800
__global__ void pack_weights(const float* w00, const float* w01, const float* w02,
                             const float* w10, const float* w11, const float* w12,
                             float* wp) {
    int i = blockIdx.x * 256 + threadIdx.x;
    if (i >= 76800) return;
    const int offs[7] = {0, 4352, 8704, 17408, 26112, 43008, 76800};
    const int cins[6] = {67, 64, 64, 67, 128, 128};
    const int kps[6]  = {68, 68, 68, 68, 132, 132};
    const float* srcs[6] = {w00, w01, w02, w10, w11, w12};
    int s = 0;
    while (i >= offs[s + 1]) ++s;
    int loc = i - offs[s];
    int kp = kps[s], cin = cins[s];
    int o = loc / kp, k = loc - o * kp;
    wp[i] = (k < cin) ? srcs[s][o * cin + k] : 0.f;
}

// ---------------- FPS ----------------
__launch_bounds__(256)
__global__ void fps_kernel(const float* pts, float* cent_ws, float* out) {
#pragma clang fp contract(off)
    const int b = blockIdx.x;
    const int tid = threadIdx.x;
    const float* px = pts + b * 3 * NPTS;
    const float* py = px + NPTS;
    const float* pz = py + NPTS;
    __shared__ __align__(16) float sx[NPTS], sy[NPTS], sz[NPTS];
    __shared__ float swv[4];
    __shared__ int swi[4];
    for (int n = tid; n < NPTS; n += 256) { sx[n] = px[n]; sy[n] = py[n]; sz[n] = pz[n]; }
    float rx[8], ry[8], rz[8], rd[8];
#pragma unroll
    for (int k = 0; k < 8; ++k) {
        int n = tid + 256 * k;
        rx[k] = px[n]; ry[k] = py[n]; rz[k] = pz[n]; rd[k] = 1e10f;
    }
    __syncthreads();
    int cur = 0;
    for (int m = 0; m < MCENT; ++m) {
        float cx = sx[cur], cy = sy[cur], cz = sz[cur];
        if (tid == 0) {
            float* cw = cent_ws + (b * MCENT + m) * 3;
            cw[0] = cx; cw[1] = cy; cw[2] = cz;
            out[b * 3 * MCENT + m] = cx;
            out[b * 3 * MCENT + MCENT + m] = cy;
            out[b * 3 * MCENT + 2 * MCENT + m] = cz;
        }
        float bestv = -1.f;
        int besti = 0;
#pragma unroll
        for (int k = 0; k < 8; ++k) {
            float dx = rx[k] - cx, dy = ry[k] - cy, dz = rz[k] - cz;
            float d2 = dx * dx + dy * dy + dz * dz;
            float nd = fminf(rd[k], d2);
            rd[k] = nd;
            if (nd > bestv) { bestv = nd; besti = tid + 256 * k; }  // k ascending -> first-index tie-break within thread
        }
#pragma unroll
        for (int off = 32; off >= 1; off >>= 1) {
            float ov = __shfl_xor(bestv, off);
            int oi = __shfl_xor(besti, off);
            if (ov > bestv || (ov == bestv && oi < besti)) { bestv = ov; besti = oi; }
        }
        int wv = tid >> 6;
        if ((tid & 63) == 0) { swv[wv] = bestv; swi[wv] = besti; }
        __syncthreads();
        bestv = swv[0]; besti = swi[0];
#pragma unroll
        for (int w = 1; w < 4; ++w) {
            float ov = swv[w]; int oi = swi[w];
            if (ov > bestv || (ov == bestv && oi < besti)) { bestv = ov; besti = oi; }
        }
        cur = besti;
        __syncthreads();
    }
}

// ---------------- MLP layers ----------------
template <int T, int S, int KP, int COUT, int OUTP>
__device__ __forceinline__ void mlp_layer(const float* IN, const float* W, const float* BI, float* OUT) {
    constexpr int NW = T / 64, HALVES = 64 / S, CoW = COUT / NW, K4 = KP / 4;
    const int lane = threadIdx.x & 63, wv = threadIdx.x >> 6;
    const int j = lane % S, half = lane / S;
    const int o0 = wv * CoW;
    float acc[CoW];
#pragma unroll
    for (int oi = 0; oi < CoW; ++oi) acc[oi] = (half == 0) ? BI[o0 + oi] : 0.f;
    for (int c4 = half; c4 < K4; c4 += HALVES) {
        float4 h4 = *reinterpret_cast<const float4*>(IN + j * KP + c4 * 4);
#pragma unroll
        for (int oi = 0; oi < CoW; ++oi) {
            const float* wr = W + (o0 + oi) * KP + c4 * 4;
            float a = acc[oi];
            a = fmaf(h4.x, wr[0], a);
            a = fmaf(h4.y, wr[1], a);
            a = fmaf(h4.z, wr[2], a);
            a = fmaf(h4.w, wr[3], a);
            acc[oi] = a;
        }
    }
#pragma unroll
    for (int oi = 0; oi < CoW; ++oi) {
        float v = acc[oi];
        if (HALVES == 2) v += __shfl_xor(v, 32);
        v = fmaxf(v, 0.f);
        if (half == 0) OUT[j * OUTP + o0 + oi] = v;
    }
}

template <int T, int S, int KP, int COUT>
__device__ __forceinline__ void mlp_final(const float* IN, const float* W, const float* BI, float* gout) {
    constexpr int NW = T / 64, HALVES = 64 / S, CoW = COUT / NW, K4 = KP / 4;
    const int lane = threadIdx.x & 63, wv = threadIdx.x >> 6;
    const int j = lane % S, half = lane / S;
    const int o0 = wv * CoW;
    float acc[CoW];
#pragma unroll
    for (int oi = 0; oi < CoW; ++oi) acc[oi] = (half == 0) ? BI[o0 + oi] : 0.f;
    for (int c4 = half; c4 < K4; c4 += HALVES) {
        float4 h4 = *reinterpret_cast<const float4*>(IN + j * KP + c4 * 4);
#pragma unroll
        for (int oi = 0; oi < CoW; ++oi) {
            const float* wr = W + (o0 + oi) * KP + c4 * 4;
            float a = acc[oi];
            a = fmaf(h4.x, wr[0], a);
            a = fmaf(h4.y, wr[1], a);
            a = fmaf(h4.z, wr[2], a);
            a = fmaf(h4.w, wr[3], a);
            acc[oi] = a;
        }
    }
#pragma unroll
    for (int oi = 0; oi < CoW; ++oi) {
        float v = acc[oi];
        if (HALVES == 2) v += __shfl_xor(v, 32);
        v = fmaxf(v, 0.f);
#pragma unroll
        for (int off = 32; off >= 1; off >>= 1) v = fmaxf(v, __shfl_xor(v, off));
        if (lane == 0) gout[(o0 + oi) * MCENT] = v;
    }
}

// ---------------- fused ball query + gather + MLP + max ----------------
template <int S, int T, int C1, int C1P, int C2, int C2P, int C3>
__global__ __launch_bounds__(T) void msg_kernel(const float* pts, const float* feats, const float* cent_ws,
                                                const float* W1, const float* B1,
                                                const float* W2, const float* B2,
                                                const float* W3, const float* B3,
                                                float* out1, int ch_off, float rr) {
    constexpr int K1P = 68;
    constexpr int PPT = NPTS / T;
    __shared__ __align__(16) float g[S * K1P];
    __shared__ __align__(16) float h1[S * C1P];
    __shared__ __align__(16) float h2[S * C2P];
    __shared__ int nbr[S];
    __shared__ int scan[T];
    const int tid = threadIdx.x;
    const int bm = blockIdx.x;
    const int b = bm / MCENT, m = bm % MCENT;
    const float cx = cent_ws[bm * 3], cy = cent_ws[bm * 3 + 1], cz = cent_ws[bm * 3 + 2];
    const float* px = pts + b * 3 * NPTS;
    const float* py = px + NPTS;
    const float* pz = py + NPTS;

    // zero the pad columns of h1/h2 (weights have zero pads, but NaN*0 = NaN, so LDS must be clean)
    for (int e = tid; e < S * 4; e += T) {
        h1[(e >> 2) * C1P + C1 + (e & 3)] = 0.f;
        h2[(e >> 2) * C2P + C2 + (e & 3)] = 0.f;
    }

    // ---- ball query: first S smallest in-ball indices (ascending) ----
    unsigned mask = 0;
    int cnt = 0;
    {
#pragma clang fp contract(off)
#pragma unroll
        for (int k = 0; k < PPT; ++k) {
            int n = tid * PPT + k;
            float dx = cx - px[n], dy = cy - py[n], dz = cz - pz[n];
            float d2 = dx * dx + dy * dy + dz * dz;
            if (d2 <= rr) { mask |= 1u << k; ++cnt; }
        }
    }
    scan[tid] = cnt;
    __syncthreads();
    for (int off = 1; off < T; off <<= 1) {
        int v = scan[tid];
        int a = (tid >= off) ? scan[tid - off] : 0;
        __syncthreads();
        scan[tid] = v + a;
        __syncthreads();
    }
    int pos = scan[tid] - cnt;  // exclusive prefix
    int total = scan[T - 1];
#pragma unroll
    for (int k = 0; k < PPT; ++k) {
        if ((mask >> k) & 1) {
            if (pos < S) nbr[pos] = tid * PPT + k;
            ++pos;
        }
    }
    __syncthreads();
    int first = nbr[0];  // centroid itself is always in-ball -> total >= 1
    for (int p = tid; p < S; p += T)
        if (p >= total) nbr[p] = first;
    __syncthreads();

    // ---- gather [rel_xyz ; feat] into LDS ----
    for (int j = tid; j < S; j += T) {
        int p = nbr[j];
        g[j * K1P + 0] = px[p] - cx;
        g[j * K1P + 1] = py[p] - cy;
        g[j * K1P + 2] = pz[p] - cz;
        g[j * K1P + 67] = 0.f;
    }
    for (int e = tid; e < S * CFEAT; e += T) {
        int j = e >> 6, c = e & 63;
        g[j * K1P + 3 + c] = feats[b * CFEAT * NPTS + c * NPTS + nbr[j]];
    }
    __syncthreads();

    // ---- MLP ----
    mlp_layer<T, S, K1P, C1, C1P>(g, W1, B1, h1);
    __syncthreads();
    mlp_layer<T, S, C1P, C2, C2P>(h1, W2, B2, h2);
    __syncthreads();
    mlp_final<T, S, C2P, C3>(h2, W3, B3, out1 + b * 384 * MCENT + ch_off * MCENT + m);
}

extern "C" void kernel_launch(void* const* d_in, const int* in_sizes, int n_in,
                              void* d_out, int out_size, void* d_ws, size_t ws_size,
                              hipStream_t stream) {
    const float* pts  = (const float*)d_in[0];
    const float* feats = (const float*)d_in[1];
    const float* w00 = (const float*)d_in[2];  const float* b00 = (const float*)d_in[3];
    const float* w01 = (const float*)d_in[4];  const float* b01 = (const float*)d_in[5];
    const float* w02 = (const float*)d_in[6];  const float* b02 = (const float*)d_in[7];
    const float* w10 = (const float*)d_in[8];  const float* b10 = (const float*)d_in[9];
    const float* w11 = (const float*)d_in[10]; const float* b11 = (const float*)d_in[11];
    const float* w12 = (const float*)d_in[12]; const float* b12 = (const float*)d_in[13];
    float* out = (float*)d_out;
    float* cent_ws = (float*)d_ws;              // 6144 floats
    float* wp = cent_ws + BATCH * MCENT * 3;    // 76800 floats

    hipLaunchKernelGGL(pack_weights, dim3(300), dim3(256), 0, stream, w00, w01, w02, w10, w11, w12, wp);
    hipLaunchKernelGGL(fps_kernel, dim3(BATCH), dim3(256), 0, stream, pts, cent_ws, out);

    float* out1 = out + BATCH * 3 * MCENT;
    const float RR0 = (float)(0.2 * 0.2);  // match Python double r*r cast to f32
    const float RR1 = (float)(0.4 * 0.4);
    hipLaunchKernelGGL((msg_kernel<32, 256, 64, 68, 64, 68, 128>), dim3(BATCH * MCENT), dim3(256), 0, stream,
                       pts, feats, cent_ws, wp + 0, b00, wp + 4352, b01, wp + 8704, b02, out1, 0, RR0);
    hipLaunchKernelGGL((msg_kernel<64, 512, 128, 132, 128, 132, 256>), dim3(BATCH * MCENT), dim3(512), 0, stream,
                       pts, feats, cent_ws, wp + 17408, b10, wp + 26112, b11, wp + 43008, b12, out1, 128, RR1);
}

// Round 2
// 622.880 us; speedup vs baseline: 2.6729x; 2.6729x over previous
//
#include <hip/hip_runtime.h>

#define NPTS 2048
#define BATCH 4
#define CFEAT 64
#define MCENT 512

typedef float f4 __attribute__((ext_vector_type(4)));
typedef short s8v __attribute__((ext_vector_type(8)));

__device__ __forceinline__ unsigned short f2bf(float x) {
    unsigned u = __float_as_uint(x);
    return (unsigned short)((u + 0x7fffu + ((u >> 16) & 1u)) >> 16);
}

// ---------------- weight packing (bf16, padded, layer0 column-permuted) ----------------
// wp layout (ushort elems): s0l0@0 (64x96), s0l1@6144 (64x64), s0l2@10240 (128x64),
// s1l0@18432 (128x96), s1l1@30720 (128x128), s1l2@47104 (256x128) -> 79872
template <int COUT, int CIN, int KPW, bool PERM>
__device__ void pack_seg(const float* w, unsigned short* dst, int start, int stride) {
    for (int i = start; i < COUT * KPW; i += stride) {
        int o = i / KPW, k = i - o * KPW;
        float v = 0.f;
        if (PERM) {  // packed col k: [0,64)=feat(src 3+k), [64,67)=xyz(src k-64), rest 0
            if (k < 64) v = w[o * CIN + 3 + k];
            else if (k < 67) v = w[o * CIN + (k - 64)];
        } else {
            if (k < CIN) v = w[o * CIN + k];
        }
        dst[i] = f2bf(v);
    }
}

// ---------------- FPS (blocks 0..3) + prep (blocks 4..) ----------------
__global__ __launch_bounds__(256) void fps_prep(
    const float* __restrict__ pts, const float* __restrict__ feats,
    const float* w00, const float* w01, const float* w02,
    const float* w10, const float* w11, const float* w12,
    float* cent, unsigned short* ftr, unsigned short* wp, float* out)
{
    const int tid = threadIdx.x;
    if (blockIdx.x >= 4) {
        const int stride = (gridDim.x - 4) * 256;
        const int start = (blockIdx.x - 4) * 256 + tid;
        // transpose feats (B,C,N) f32 -> (B,N,C) bf16
        for (int i = start; i < BATCH * NPTS * CFEAT; i += stride) {
            int c = i & 63, n = (i >> 6) & (NPTS - 1), b = i >> 17;
            ftr[i] = f2bf(feats[(b * CFEAT + c) * NPTS + n]);
        }
        pack_seg<64, 67, 96, true>(w00, wp + 0, start, stride);
        pack_seg<64, 64, 64, false>(w01, wp + 6144, start, stride);
        pack_seg<128, 64, 64, false>(w02, wp + 10240, start, stride);
        pack_seg<128, 67, 96, true>(w10, wp + 18432, start, stride);
        pack_seg<128, 128, 128, false>(w11, wp + 30720, start, stride);
        pack_seg<256, 128, 128, false>(w12, wp + 47104, start, stride);
        return;
    }
    const int b = blockIdx.x;
    const int wv = tid >> 6;
    const float* px = pts + b * 3 * NPTS;
    const float* py = px + NPTS;
    const float* pz = py + NPTS;
    __shared__ float slots[2][4][8];
    float rx[8], ry[8], rz[8], rd[8];
#pragma unroll
    for (int k = 0; k < 8; ++k) {
        int n = tid * 8 + k;
        rx[k] = px[n]; ry[k] = py[n]; rz[k] = pz[n]; rd[k] = 1e10f;
    }
    float cx = px[0], cy = py[0], cz = pz[0];
    float* outc = out + b * 3 * MCENT;
    for (int m = 0; m < MCENT; ++m) {
        if (tid == 0) {
            float* cw = cent + (b * MCENT + m) * 3;
            cw[0] = cx; cw[1] = cy; cw[2] = cz;
            outc[m] = cx; outc[MCENT + m] = cy; outc[2 * MCENT + m] = cz;
        }
        float bv = -1.f; int bi = 0;
        {
#pragma clang fp contract(off)
#pragma unroll
            for (int k = 0; k < 8; ++k) {
                float dx = rx[k] - cx, dy = ry[k] - cy, dz = rz[k] - cz;
                float d2 = dx * dx + dy * dy;
                d2 = d2 + dz * dz;
                float nd = fminf(rd[k], d2);
                rd[k] = nd;
                if (nd > bv) { bv = nd; bi = tid * 8 + k; }  // k asc -> first-index tie-break
            }
        }
#pragma unroll
        for (int off = 32; off >= 1; off >>= 1) {
            float ov = __shfl_xor(bv, off);
            int oi = __shfl_xor(bi, off);
            if (ov > bv || (ov == bv && oi < bi)) { bv = ov; bi = oi; }
        }
        // winning lane's point coords (register select, static indices)
        float ox = rx[0], oy = ry[0], oz = rz[0];
        int kk = bi & 7;
#pragma unroll
        for (int k = 1; k < 8; ++k) {
            ox = (kk == k) ? rx[k] : ox;
            oy = (kk == k) ? ry[k] : oy;
            oz = (kk == k) ? rz[k] : oz;
        }
        int par = m & 1;
        if ((bi >> 3) == tid) {
            slots[par][wv][0] = bv;
            slots[par][wv][1] = __int_as_float(bi);
            slots[par][wv][2] = ox; slots[par][wv][3] = oy; slots[par][wv][4] = oz;
        }
        __syncthreads();  // single barrier per step (parity double-buffer)
        float bw = slots[par][0][0]; int ii = __float_as_int(slots[par][0][1]);
        cx = slots[par][0][2]; cy = slots[par][0][3]; cz = slots[par][0][4];
#pragma unroll
        for (int w = 1; w < 4; ++w) {
            float vv = slots[par][w][0]; int wi = __float_as_int(slots[par][w][1]);
            float nx = slots[par][w][2], ny = slots[par][w][3], nz = slots[par][w][4];
            bool better = (vv > bw) || (vv == bw && wi < ii);
            if (better) { bw = vv; ii = wi; cx = nx; cy = ny; cz = nz; }
        }
    }
}

// ---------------- MFMA MLP layer ----------------
// A in LDS: rows [S][KP] bf16, XOR-swizzled (byte ^= (row&7)<<4).
// W in global: [COUT][KP] bf16 row-major (B^T layout). D col = lane&15 (=n), row = 4*(lane>>4)+reg (=j).
template <int MT, int KSTEPS, int NTW>
__device__ __forceinline__ void layer_mm(const unsigned short* A, const unsigned short* __restrict__ Wg,
                                         const float* __restrict__ bias, int lane, int wv,
                                         f4 (&acc)[MT][NTW])
{
    constexpr int KP = KSTEPS * 32;
    const int r15 = lane & 15, g = lane >> 4;
#pragma unroll
    for (int nt = 0; nt < NTW; ++nt) {
        int n = (wv * NTW + nt) * 16 + r15;
        float bv = bias[n];
#pragma unroll
        for (int mt = 0; mt < MT; ++mt) acc[mt][nt] = (f4){bv, bv, bv, bv};
    }
#pragma unroll
    for (int ks = 0; ks < KSTEPS; ++ks) {
        s8v afr[MT];
#pragma unroll
        for (int mt = 0; mt < MT; ++mt) {
            int row = mt * 16 + r15;
            int byte = ((row * KP + ks * 32 + g * 8) * 2) ^ ((row & 7) << 4);
            afr[mt] = *(const s8v*)((const char*)A + byte);
        }
#pragma unroll
        for (int nt = 0; nt < NTW; ++nt) {
            int n = (wv * NTW + nt) * 16 + r15;
            s8v bfr = *(const s8v*)(Wg + n * KP + ks * 32 + g * 8);
#pragma unroll
            for (int mt = 0; mt < MT; ++mt)
                acc[mt][nt] = __builtin_amdgcn_mfma_f32_16x16x32_bf16(afr[mt], bfr, acc[mt][nt], 0, 0, 0);
        }
    }
}

template <int MT, int NTW, int CO>
__device__ __forceinline__ void store_lds(f4 (&acc)[MT][NTW], unsigned short* OUT, int lane, int wv) {
    const int r15 = lane & 15, g = lane >> 4;
#pragma unroll
    for (int mt = 0; mt < MT; ++mt)
#pragma unroll
        for (int nt = 0; nt < NTW; ++nt)
#pragma unroll
            for (int q = 0; q < 4; ++q) {
                int j = mt * 16 + g * 4 + q;
                int n = (wv * NTW + nt) * 16 + r15;
                float v = fmaxf(acc[mt][nt][q], 0.f);
                int byte = ((j * CO + n) * 2) ^ ((j & 7) << 4);
                *(unsigned short*)((char*)OUT + byte) = f2bf(v);
            }
}

// ---------------- fused ball query + gather + MFMA MLP + max ----------------
template <int S_, int C1, int C2, int C3>
__global__ __launch_bounds__(256) void msg_mfma(
    const float* __restrict__ pts, const unsigned short* __restrict__ ftr,
    const float* __restrict__ cent,
    const unsigned short* __restrict__ W0, const float* __restrict__ B0,
    const unsigned short* __restrict__ W1, const float* __restrict__ B1,
    const unsigned short* __restrict__ W2, const float* __restrict__ B2,
    float* __restrict__ outf, int ch_off, float rr)
{
    constexpr int MT = S_ / 16;
    constexpr int KS1 = C1 / 32, KS2 = C2 / 32;
    constexpr int NW1 = C1 / 64, NW2 = C2 / 64, NW3 = C3 / 64;
    constexpr int HA = (S_ * 96 > S_ * C2) ? S_ * 96 : S_ * C2;
    __shared__ __align__(16) unsigned short hA[HA];      // g, later h2 (aliased)
    __shared__ __align__(16) unsigned short hB[S_ * C1]; // h1
    __shared__ int nbr[S_];
    __shared__ int wtot[4];
    const int tid = threadIdx.x, lane = tid & 63, wv = tid >> 6;
    const int bm = blockIdx.x, b = bm >> 9, m = bm & (MCENT - 1);
    const float cx = cent[bm * 3], cy = cent[bm * 3 + 1], cz = cent[bm * 3 + 2];
    const float* px = pts + b * 3 * NPTS;
    const float* py = px + NPTS;
    const float* pz = py + NPTS;

    // ---- ball query: first S smallest in-ball indices (ascending) ----
    unsigned mask = 0; int cnt = 0;
    {
#pragma clang fp contract(off)
#pragma unroll
        for (int k = 0; k < 8; ++k) {
            int n = tid * 8 + k;
            float dx = cx - px[n], dy = cy - py[n], dz = cz - pz[n];
            float d2 = dx * dx + dy * dy;
            d2 = d2 + dz * dz;
            if (d2 <= rr) { mask |= 1u << k; ++cnt; }
        }
    }
    int inc = cnt;
#pragma unroll
    for (int off = 1; off < 64; off <<= 1) {
        int t = __shfl_up(inc, off);
        if (lane >= off) inc += t;
    }
    if (lane == 63) wtot[wv] = inc;
    __syncthreads();
    int base = 0, tot = 0;
#pragma unroll
    for (int w = 0; w < 4; ++w) { int t = wtot[w]; tot += t; if (w < wv) base += t; }
    int pos = base + inc - cnt;
#pragma unroll
    for (int k = 0; k < 8; ++k) {
        if ((mask >> k) & 1) {
            if (pos < S_) nbr[pos] = tid * 8 + k;
            ++pos;
        }
    }
    __syncthreads();
    const int first = nbr[0];  // centroid always in its own ball -> tot >= 1

    // ---- gather: rows = [feat(64) ; rel_xyz(3) ; pad -> 96] bf16, swizzled ----
    for (int e = tid; e < S_ * 8; e += 256) {
        int j = e >> 3, c8 = e & 7;
        int p = (j < tot) ? nbr[j] : first;
        s8v v = *(const s8v*)(ftr + (b * NPTS + p) * 64 + c8 * 8);
        int byte = ((j * 96 + c8 * 8) * 2) ^ ((j & 7) << 4);
        *(s8v*)((char*)hA + byte) = v;
    }
    for (int e = tid; e < S_ * 4; e += 256) {
        int j = e >> 2, q = e & 3;
        int p = (j < tot) ? nbr[j] : first;
        s8v v = {0, 0, 0, 0, 0, 0, 0, 0};
        if (q == 0) {
            v[0] = (short)f2bf(px[p] - cx);
            v[1] = (short)f2bf(py[p] - cy);
            v[2] = (short)f2bf(pz[p] - cz);
        }
        int byte = ((j * 96 + 64 + q * 8) * 2) ^ ((j & 7) << 4);
        *(s8v*)((char*)hA + byte) = v;
    }
    __syncthreads();

    // ---- MLP: 3 MFMA layers ----
    {
        f4 acc[MT][NW1];
        layer_mm<MT, 3, NW1>(hA, W0, B0, lane, wv, acc);
        store_lds<MT, NW1, C1>(acc, hB, lane, wv);
    }
    __syncthreads();
    {
        f4 acc[MT][NW2];
        layer_mm<MT, KS1, NW2>(hB, W1, B1, lane, wv, acc);
        store_lds<MT, NW2, C2>(acc, hA, lane, wv);
    }
    __syncthreads();
    {
        f4 acc[MT][NW3];
        layer_mm<MT, KS2, NW3>(hA, W2, B2, lane, wv, acc);
        const int r15 = lane & 15;
        float* dst = outf + b * 384 * MCENT + ch_off * MCENT + m;
#pragma unroll
        for (int nt = 0; nt < NW3; ++nt) {
            float mv = -1e30f;
#pragma unroll
            for (int mt = 0; mt < MT; ++mt)
#pragma unroll
                for (int q = 0; q < 4; ++q) mv = fmaxf(mv, acc[mt][nt][q]);
            mv = fmaxf(mv, __shfl_xor(mv, 16));
            mv = fmaxf(mv, __shfl_xor(mv, 32));
            float v = fmaxf(mv, 0.f);  // relu(max) == max(relu)
            if (lane < 16) dst[((wv * NW3 + nt) * 16 + r15) * MCENT] = v;
        }
    }
}

extern "C" void kernel_launch(void* const* d_in, const int* in_sizes, int n_in,
                              void* d_out, int out_size, void* d_ws, size_t ws_size,
                              hipStream_t stream) {
    const float* pts  = (const float*)d_in[0];
    const float* feats = (const float*)d_in[1];
    const float* w00 = (const float*)d_in[2];  const float* b00 = (const float*)d_in[3];
    const float* w01 = (const float*)d_in[4];  const float* b01 = (const float*)d_in[5];
    const float* w02 = (const float*)d_in[6];  const float* b02 = (const float*)d_in[7];
    const float* w10 = (const float*)d_in[8];  const float* b10 = (const float*)d_in[9];
    const float* w11 = (const float*)d_in[10]; const float* b11 = (const float*)d_in[11];
    const float* w12 = (const float*)d_in[12]; const float* b12 = (const float*)d_in[13];
    float* out = (float*)d_out;
    char* ws = (char*)d_ws;
    float* cent = (float*)ws;                                   // 24576 B
    unsigned short* ftr = (unsigned short*)(ws + 24576);        // 1048576 B
    unsigned short* wp  = (unsigned short*)(ws + 24576 + 1048576);  // 159744 B

    hipLaunchKernelGGL(fps_prep, dim3(68), dim3(256), 0, stream,
                       pts, feats, w00, w01, w02, w10, w11, w12, cent, ftr, wp, out);
    float* outf = out + BATCH * 3 * MCENT;
    const float RR0 = (float)(0.2 * 0.2);
    const float RR1 = (float)(0.4 * 0.4);
    hipLaunchKernelGGL((msg_mfma<32, 64, 64, 128>), dim3(BATCH * MCENT), dim3(256), 0, stream,
                       pts, ftr, cent, wp + 0, b00, wp + 6144, b01, wp + 10240, b02, outf, 0, RR0);
    hipLaunchKernelGGL((msg_mfma<64, 128, 128, 256>), dim3(BATCH * MCENT), dim3(256), 0, stream,
                       pts, ftr, cent, wp + 18432, b10, wp + 30720, b11, wp + 47104, b12, outf, 128, RR1);
}

// Round 3
// 439.854 us; speedup vs baseline: 3.7851x; 1.4161x over previous
//
#include <hip/hip_runtime.h>

#define NPTS 2048
#define BATCH 4
#define CFEAT 64
#define MCENT 512

typedef float f4 __attribute__((ext_vector_type(4)));
typedef float f2 __attribute__((ext_vector_type(2)));
typedef short s8v __attribute__((ext_vector_type(8)));

__device__ __forceinline__ unsigned short f2bf(float x) {
    unsigned u = __float_as_uint(x);
    return (unsigned short)((u + 0x7fffu + ((u >> 16) & 1u)) >> 16);
}

template <int CTRL>
__device__ __forceinline__ float dpp_max_step(float v) {
    int t = __builtin_amdgcn_update_dpp(0, __float_as_int(v), CTRL, 0xf, 0xf, true);
    return fmaxf(v, __int_as_float(t));
}

// ---------------- weight packing (bf16, padded, layer0 column-permuted) ----------------
// wp (ushort elems): s0l0@0 (64x96), s0l1@6144 (64x64), s0l2@10240 (128x64),
// s1l0@18432 (128x96), s1l1@30720 (128x128), s1l2@47104 (256x128) -> 79872
template <int COUT, int CIN, int KPW, bool PERM>
__device__ void pack_seg(const float* w, unsigned short* dst, int start, int stride) {
    for (int i = start; i < COUT * KPW; i += stride) {
        int o = i / KPW, k = i - o * KPW;
        float v = 0.f;
        if (PERM) {  // packed col k: [0,64)=feat(src 3+k), [64,67)=xyz(src k-64), rest 0
            if (k < 64) v = w[o * CIN + 3 + k];
            else if (k < 67) v = w[o * CIN + (k - 64)];
        } else {
            if (k < CIN) v = w[o * CIN + k];
        }
        dst[i] = f2bf(v);
    }
}

// ---------------- FPS (blocks 0..3, wave 0) + prep (blocks 4..67) ----------------
__global__ __launch_bounds__(256, 1) void fps_prep(
    const float* __restrict__ pts, const float* __restrict__ feats,
    const float* w00, const float* w01, const float* w02,
    const float* w10, const float* w11, const float* w12,
    float* cent, unsigned short* ftr, unsigned short* wp, float* out)
{
    const int tid = threadIdx.x;
    if (blockIdx.x >= 4) {
        const int stride = 64 * 256;
        const int start = (blockIdx.x - 4) * 256 + tid;
        for (int i = start; i < BATCH * NPTS * CFEAT; i += stride) {
            int c = i & 63, n = (i >> 6) & (NPTS - 1), b = i >> 17;
            ftr[i] = f2bf(feats[(b * CFEAT + c) * NPTS + n]);
        }
        pack_seg<64, 67, 96, true>(w00, wp + 0, start, stride);
        pack_seg<64, 64, 64, false>(w01, wp + 6144, start, stride);
        pack_seg<128, 64, 64, false>(w02, wp + 10240, start, stride);
        pack_seg<128, 67, 96, true>(w10, wp + 18432, start, stride);
        pack_seg<128, 128, 128, false>(w11, wp + 30720, start, stride);
        pack_seg<256, 128, 128, false>(w12, wp + 47104, start, stride);
        return;
    }
    __shared__ __align__(16) float4 sp[NPTS];  // 32 KB point table (coords exact f32)
    const int b = blockIdx.x;
    const float* px = pts + b * 3 * NPTS;
    const float* py = px + NPTS;
    const float* pz = py + NPTS;
    for (int i = tid; i < NPTS; i += 256) sp[i] = make_float4(px[i], py[i], pz[i], 0.f);
    __syncthreads();            // waves 1..3 exit after this; wave 0 runs barrier-free
    if (tid >= 64) return;

    f2 rx[16], ry[16], rz[16], rd[16];
#pragma unroll
    for (int i = 0; i < 16; ++i) {
        float4 a = sp[tid * 32 + 2 * i];
        float4 c = sp[tid * 32 + 2 * i + 1];
        rx[i] = (f2){a.x, c.x}; ry[i] = (f2){a.y, c.y}; rz[i] = (f2){a.z, c.z};
        rd[i] = (f2){1e10f, 1e10f};
    }
    float4 c0 = sp[0];
    float cx = c0.x, cy = c0.y, cz = c0.z;
    float* outc = out + b * 3 * MCENT;
    for (int m = 0; m < MCENT; ++m) {
        if (tid == 0) {
            float* cw = cent + (b * MCENT + m) * 3;
            cw[0] = cx; cw[1] = cy; cw[2] = cz;
            outc[m] = cx; outc[MCENT + m] = cy; outc[2 * MCENT + m] = cz;
        }
        float bvE = -1.f, bvO = -1.f;
        int biE = 0, biO = 0;
        {
#pragma clang fp contract(off)
            f2 c2x = {cx, cx}, c2y = {cy, cy}, c2z = {cz, cz};
#pragma unroll
            for (int i = 0; i < 16; ++i) {
                f2 dx = rx[i] - c2x, dy = ry[i] - c2y, dz = rz[i] - c2z;
                f2 d2 = dx * dx + dy * dy;   // contract off: mul,mul,add (numpy order)
                d2 = d2 + dz * dz;
                f2 old = rd[i];
                f2 nd;
                nd.x = fminf(old.x, d2.x);
                nd.y = fminf(old.y, d2.y);
                rd[i] = nd;
                int base = tid * 32 + 2 * i;
                if (nd.x > bvE) { bvE = nd.x; biE = base; }       // strict >, k asc
                if (nd.y > bvO) { bvO = nd.y; biO = base + 1; }
            }
        }
        bool eW = (bvE > bvO) || (bvE == bvO && biE < biO);
        float bv = eW ? bvE : bvO;
        int bi = eW ? biE : biO;
        // DPP wave max -> lane 63
        float v = bv;
        v = dpp_max_step<0x111>(v);  // row_shr:1
        v = dpp_max_step<0x112>(v);  // row_shr:2
        v = dpp_max_step<0x114>(v);  // row_shr:4
        v = dpp_max_step<0x118>(v);  // row_shr:8
        v = dpp_max_step<0x142>(v);  // row_bcast:15
        v = dpp_max_step<0x143>(v);  // row_bcast:31
        float wmax = __int_as_float(__builtin_amdgcn_readlane(__float_as_int(v), 63));
        unsigned long long cand = __ballot(bv == wmax);
        int wl = __ffsll(cand) - 1;                  // lowest candidate lane = smallest index
        int idx = __builtin_amdgcn_readlane(bi, wl);
        float4 cc = sp[idx];                         // uniform ds_read_b128
        cx = cc.x; cy = cc.y; cz = cc.z;
    }
}

// ---------------- MFMA MLP layer ----------------
template <int MT, int KSTEPS, int NTW>
__device__ __forceinline__ void layer_mm(const unsigned short* A, const unsigned short* __restrict__ Wg,
                                         const float* __restrict__ bias, int lane, int wv,
                                         f4 (&acc)[MT][NTW])
{
    constexpr int KP = KSTEPS * 32;
    const int r15 = lane & 15, g = lane >> 4;
#pragma unroll
    for (int nt = 0; nt < NTW; ++nt) {
        int n = (wv * NTW + nt) * 16 + r15;
        float bv = bias[n];
#pragma unroll
        for (int mt = 0; mt < MT; ++mt) acc[mt][nt] = (f4){bv, bv, bv, bv};
    }
#pragma unroll
    for (int ks = 0; ks < KSTEPS; ++ks) {
        s8v afr[MT];
#pragma unroll
        for (int mt = 0; mt < MT; ++mt) {
            int row = mt * 16 + r15;
            int byte = ((row * KP + ks * 32 + g * 8) * 2) ^ ((row & 7) << 4);
            afr[mt] = *(const s8v*)((const char*)A + byte);
        }
#pragma unroll
        for (int nt = 0; nt < NTW; ++nt) {
            int n = (wv * NTW + nt) * 16 + r15;
            s8v bfr = *(const s8v*)(Wg + n * KP + ks * 32 + g * 8);
#pragma unroll
            for (int mt = 0; mt < MT; ++mt)
                acc[mt][nt] = __builtin_amdgcn_mfma_f32_16x16x32_bf16(afr[mt], bfr, acc[mt][nt], 0, 0, 0);
        }
    }
}

template <int MT, int NTW, int CO>
__device__ __forceinline__ void store_lds(f4 (&acc)[MT][NTW], unsigned short* OUT, int lane, int wv) {
    const int r15 = lane & 15, g = lane >> 4;
#pragma unroll
    for (int mt = 0; mt < MT; ++mt)
#pragma unroll
        for (int nt = 0; nt < NTW; ++nt)
#pragma unroll
            for (int q = 0; q < 4; ++q) {
                int j = mt * 16 + g * 4 + q;
                int n = (wv * NTW + nt) * 16 + r15;
                float v = fmaxf(acc[mt][nt][q], 0.f);
                int byte = ((j * CO + n) * 2) ^ ((j & 7) << 4);
                *(unsigned short*)((char*)OUT + byte) = f2bf(v);
            }
}

// ---------------- fused ball query + gather + MFMA MLP + max ----------------
template <int S_, int C1, int C2, int C3>
__device__ __forceinline__ void msg_body(int bm, char* smem,
    const float* __restrict__ pts, const unsigned short* __restrict__ ftr,
    const float* __restrict__ cent,
    const unsigned short* __restrict__ W0, const float* __restrict__ B0,
    const unsigned short* __restrict__ W1, const float* __restrict__ B1,
    const unsigned short* __restrict__ W2, const float* __restrict__ B2,
    float* __restrict__ outf, int ch_off, float rr)
{
    constexpr int MT = S_ / 16;
    constexpr int KS1 = C1 / 32, KS2 = C2 / 32;
    constexpr int NW1 = C1 / 64, NW2 = C2 / 64, NW3 = C3 / 64;
    constexpr int HA = (S_ * 96 > S_ * C2) ? S_ * 96 : S_ * C2;
    unsigned short* hA = (unsigned short*)smem;
    unsigned short* hB = hA + HA;
    int* nbr = (int*)(hB + S_ * C1);
    int* wtot = nbr + S_;
    const int tid = threadIdx.x, lane = tid & 63, wv = tid >> 6;
    const int b = bm >> 9, m = bm & (MCENT - 1);
    const float cx = cent[bm * 3], cy = cent[bm * 3 + 1], cz = cent[bm * 3 + 2];
    const float* px = pts + b * 3 * NPTS;
    const float* py = px + NPTS;
    const float* pz = py + NPTS;

    // ---- ball query: first S smallest in-ball indices (ascending) ----
    unsigned mask = 0; int cnt = 0;
    {
#pragma clang fp contract(off)
#pragma unroll
        for (int k = 0; k < 8; ++k) {
            int n = tid * 8 + k;
            float dx = cx - px[n], dy = cy - py[n], dz = cz - pz[n];
            float d2 = dx * dx + dy * dy;
            d2 = d2 + dz * dz;
            if (d2 <= rr) { mask |= 1u << k; ++cnt; }
        }
    }
    int inc = cnt;
#pragma unroll
    for (int off = 1; off < 64; off <<= 1) {
        int t = __shfl_up(inc, off);
        if (lane >= off) inc += t;
    }
    if (lane == 63) wtot[wv] = inc;
    __syncthreads();
    int base = 0, tot = 0;
#pragma unroll
    for (int w = 0; w < 4; ++w) { int t = wtot[w]; tot += t; if (w < wv) base += t; }
    int pos = base + inc - cnt;
#pragma unroll
    for (int k = 0; k < 8; ++k) {
        if ((mask >> k) & 1) {
            if (pos < S_) nbr[pos] = tid * 8 + k;
            ++pos;
        }
    }
    __syncthreads();
    const int first = nbr[0];

    // ---- gather: rows = [feat(64) ; rel_xyz(3) ; pad -> 96] bf16, swizzled ----
    for (int e = tid; e < S_ * 8; e += 256) {
        int j = e >> 3, c8 = e & 7;
        int p = (j < tot) ? nbr[j] : first;
        s8v v = *(const s8v*)(ftr + (b * NPTS + p) * 64 + c8 * 8);
        int byte = ((j * 96 + c8 * 8) * 2) ^ ((j & 7) << 4);
        *(s8v*)((char*)hA + byte) = v;
    }
    for (int e = tid; e < S_ * 4; e += 256) {
        int j = e >> 2, q = e & 3;
        int p = (j < tot) ? nbr[j] : first;
        s8v v = {0, 0, 0, 0, 0, 0, 0, 0};
        if (q == 0) {
            v[0] = (short)f2bf(px[p] - cx);
            v[1] = (short)f2bf(py[p] - cy);
            v[2] = (short)f2bf(pz[p] - cz);
        }
        int byte = ((j * 96 + 64 + q * 8) * 2) ^ ((j & 7) << 4);
        *(s8v*)((char*)hA + byte) = v;
    }
    __syncthreads();

    // ---- MLP: 3 MFMA layers ----
    {
        f4 acc[MT][NW1];
        layer_mm<MT, 3, NW1>(hA, W0, B0, lane, wv, acc);
        store_lds<MT, NW1, C1>(acc, hB, lane, wv);
    }
    __syncthreads();
    {
        f4 acc[MT][NW2];
        layer_mm<MT, KS1, NW2>(hB, W1, B1, lane, wv, acc);
        store_lds<MT, NW2, C2>(acc, hA, lane, wv);
    }
    __syncthreads();
    {
        f4 acc[MT][NW3];
        layer_mm<MT, KS2, NW3>(hA, W2, B2, lane, wv, acc);
        const int r15 = lane & 15;
        float* dst = outf + b * 384 * MCENT + ch_off * MCENT + m;
#pragma unroll
        for (int nt = 0; nt < NW3; ++nt) {
            float mv = -1e30f;
#pragma unroll
            for (int mt = 0; mt < MT; ++mt)
#pragma unroll
                for (int q = 0; q < 4; ++q) mv = fmaxf(mv, acc[mt][nt][q]);
            mv = fmaxf(mv, __shfl_xor(mv, 16));
            mv = fmaxf(mv, __shfl_xor(mv, 32));
            float v = fmaxf(mv, 0.f);
            if (lane < 16) dst[((wv * NW3 + nt) * 16 + r15) * MCENT] = v;
        }
    }
}

__global__ __launch_bounds__(256) void msg_both(
    const float* __restrict__ pts, const unsigned short* __restrict__ ftr,
    const float* __restrict__ cent, const unsigned short* __restrict__ wp,
    const float* __restrict__ b00, const float* __restrict__ b01, const float* __restrict__ b02,
    const float* __restrict__ b10, const float* __restrict__ b11, const float* __restrict__ b12,
    float* __restrict__ outf, float rr0, float rr1)
{
    extern __shared__ __align__(16) char smem[];
    if (blockIdx.x < BATCH * MCENT)
        msg_body<32, 64, 64, 128>(blockIdx.x, smem, pts, ftr, cent,
                                  wp + 0, b00, wp + 6144, b01, wp + 10240, b02, outf, 0, rr0);
    else
        msg_body<64, 128, 128, 256>(blockIdx.x - BATCH * MCENT, smem, pts, ftr, cent,
                                    wp + 18432, b10, wp + 30720, b11, wp + 47104, b12, outf, 128, rr1);
}

extern "C" void kernel_launch(void* const* d_in, const int* in_sizes, int n_in,
                              void* d_out, int out_size, void* d_ws, size_t ws_size,
                              hipStream_t stream) {
    const float* pts  = (const float*)d_in[0];
    const float* feats = (const float*)d_in[1];
    const float* w00 = (const float*)d_in[2];  const float* b00 = (const float*)d_in[3];
    const float* w01 = (const float*)d_in[4];  const float* b01 = (const float*)d_in[5];
    const float* w02 = (const float*)d_in[6];  const float* b02 = (const float*)d_in[7];
    const float* w10 = (const float*)d_in[8];  const float* b10 = (const float*)d_in[9];
    const float* w11 = (const float*)d_in[10]; const float* b11 = (const float*)d_in[11];
    const float* w12 = (const float*)d_in[12]; const float* b12 = (const float*)d_in[13];
    float* out = (float*)d_out;
    char* ws = (char*)d_ws;
    float* cent = (float*)ws;                                       // 24576 B
    unsigned short* ftr = (unsigned short*)(ws + 24576);            // 1048576 B
    unsigned short* wp  = (unsigned short*)(ws + 24576 + 1048576);  // 159744 B

    hipLaunchKernelGGL(fps_prep, dim3(68), dim3(256), 0, stream,
                       pts, feats, w00, w01, w02, w10, w11, w12, cent, ftr, wp, out);
    float* outf = out + BATCH * 3 * MCENT;
    const float RR0 = (float)(0.2 * 0.2);
    const float RR1 = (float)(0.4 * 0.4);
    hipLaunchKernelGGL(msg_both, dim3(2 * BATCH * MCENT), dim3(256), 33040, stream,
                       pts, ftr, cent, wp, b00, b01, b02, b10, b11, b12, outf, RR0, RR1);
}

// Round 4
// 369.652 us; speedup vs baseline: 4.5039x; 1.1899x over previous
//
#include <hip/hip_runtime.h>

#define NPTS 2048
#define BATCH 4
#define CFEAT 64
#define MCENT 512

typedef float f4 __attribute__((ext_vector_type(4)));
typedef float f2 __attribute__((ext_vector_type(2)));
typedef short s8v __attribute__((ext_vector_type(8)));

__device__ __forceinline__ unsigned short f2bf(float x) {
    unsigned u = __float_as_uint(x);
    return (unsigned short)((u + 0x7fffu + ((u >> 16) & 1u)) >> 16);
}

template <int CTRL>
__device__ __forceinline__ float dpp_max_step(float v) {
    int t = __builtin_amdgcn_update_dpp(0, __float_as_int(v), CTRL, 0xf, 0xf, true);
    return fmaxf(v, __int_as_float(t));
}

// ---------------- weight packing (bf16, padded, layer0 column-permuted) ----------------
// wp (ushort elems): s0l0@0 (64x96), s0l1@6144 (64x64), s0l2@10240 (128x64),
// s1l0@18432 (128x96), s1l1@30720 (128x128), s1l2@47104 (256x128) -> 79872
template <int COUT, int CIN, int KPW, bool PERM>
__device__ void pack_seg(const float* w, unsigned short* dst, int start, int stride) {
    for (int i = start; i < COUT * KPW; i += stride) {
        int o = i / KPW, k = i - o * KPW;
        float v = 0.f;
        if (PERM) {  // packed col k: [0,64)=feat(src 3+k), [64,67)=xyz(src k-64), rest 0
            if (k < 64) v = w[o * CIN + 3 + k];
            else if (k < 67) v = w[o * CIN + (k - 64)];
        } else {
            if (k < CIN) v = w[o * CIN + k];
        }
        dst[i] = f2bf(v);
    }
}

// ---------------- FPS (blocks 0..3, 4 waves cooperative) + prep (blocks 4..67) ----------------
__global__ __launch_bounds__(256, 1) void fps_prep(
    const float* __restrict__ pts, const float* __restrict__ feats,
    const float* w00, const float* w01, const float* w02,
    const float* w10, const float* w11, const float* w12,
    float* cent, unsigned short* ftr, unsigned short* wp, float* out)
{
    const int tid = threadIdx.x;
    if (blockIdx.x >= 4) {
        const int stride = 64 * 256;
        const int start = (blockIdx.x - 4) * 256 + tid;
        for (int i = start; i < BATCH * NPTS * CFEAT; i += stride) {
            int c = i & 63, n = (i >> 6) & (NPTS - 1), b = i >> 17;
            ftr[i] = f2bf(feats[(b * CFEAT + c) * NPTS + n]);
        }
        pack_seg<64, 67, 96, true>(w00, wp + 0, start, stride);
        pack_seg<64, 64, 64, false>(w01, wp + 6144, start, stride);
        pack_seg<128, 64, 64, false>(w02, wp + 10240, start, stride);
        pack_seg<128, 67, 96, true>(w10, wp + 18432, start, stride);
        pack_seg<128, 128, 128, false>(w11, wp + 30720, start, stride);
        pack_seg<256, 128, 128, false>(w12, wp + 47104, start, stride);
        return;
    }
    const int b = blockIdx.x;
    const int lane = tid & 63, wv = tid >> 6;
    const float* px = pts + b * 3 * NPTS;
    const float* py = px + NPTS;
    const float* pz = py + NPTS;
    __shared__ __align__(16) float slots[2][4][8];  // [parity][wave][val,idx,x,y,z,_,_,_]

    // wave wv owns points [wv*512, wv*512+512); lane owns 8 (4 f2 pairs, even/odd)
    const int base = wv * 512 + lane * 8;
    f2 rx[4], ry[4], rz[4], rd[4];
#pragma unroll
    for (int i = 0; i < 4; ++i) {
        rx[i] = *(const f2*)(px + base + 2 * i);
        ry[i] = *(const f2*)(py + base + 2 * i);
        rz[i] = *(const f2*)(pz + base + 2 * i);
        rd[i] = (f2){1e10f, 1e10f};
    }
    float cx = px[0], cy = py[0], cz = pz[0];
    float* outc = out + b * 3 * MCENT;
    int par = 0;
    for (int m = 0; m < MCENT; ++m) {
        if (tid == 0) {
            float* cw = cent + (b * MCENT + m) * 3;
            cw[0] = cx; cw[1] = cy; cw[2] = cz;
            outc[m] = cx; outc[MCENT + m] = cy; outc[2 * MCENT + m] = cz;
        }
        float bvE = -1.f, bvO = -1.f;
        int biE = 0, biO = 0;
        {
#pragma clang fp contract(off)
            f2 c2x = {cx, cx}, c2y = {cy, cy}, c2z = {cz, cz};
#pragma unroll
            for (int i = 0; i < 4; ++i) {
                f2 dx = rx[i] - c2x, dy = ry[i] - c2y, dz = rz[i] - c2z;
                f2 d2 = dx * dx + dy * dy;   // contract off: mul,mul,add (numpy order)
                d2 = d2 + dz * dz;
                f2 old = rd[i];
                f2 nd;
                nd.x = fminf(old.x, d2.x);
                nd.y = fminf(old.y, d2.y);
                rd[i] = nd;
                int bb = base + 2 * i;
                if (nd.x > bvE) { bvE = nd.x; biE = bb; }       // strict >, k asc
                if (nd.y > bvO) { bvO = nd.y; biO = bb + 1; }
            }
        }
        bool eW = (bvE > bvO) || (bvE == bvO && biE < biO);
        float bv = eW ? bvE : bvO;
        int bi = eW ? biE : biO;
        // candidate coords from registers (independent of reduce -> overlaps)
        int kk = bi & 7;
        float ox = rx[0].x, oy = ry[0].x, oz = rz[0].x;
#pragma unroll
        for (int k = 1; k < 8; ++k) {
            float nx = (k & 1) ? rx[k >> 1].y : rx[k >> 1].x;
            float ny = (k & 1) ? ry[k >> 1].y : ry[k >> 1].x;
            float nz = (k & 1) ? rz[k >> 1].y : rz[k >> 1].x;
            ox = (kk == k) ? nx : ox;
            oy = (kk == k) ? ny : oy;
            oz = (kk == k) ? nz : oz;
        }
        // DPP wave max -> lane 63
        float v = bv;
        v = dpp_max_step<0x111>(v);  // row_shr:1
        v = dpp_max_step<0x112>(v);  // row_shr:2
        v = dpp_max_step<0x114>(v);  // row_shr:4
        v = dpp_max_step<0x118>(v);  // row_shr:8
        v = dpp_max_step<0x142>(v);  // row_bcast:15
        v = dpp_max_step<0x143>(v);  // row_bcast:31
        float wmax = __int_as_float(__builtin_amdgcn_readlane(__float_as_int(v), 63));
        unsigned long long cand = __ballot(bv == wmax);
        int wl = __ffsll(cand) - 1;                  // lowest lane = smallest index
        if (lane == wl) {
            *(float4*)&slots[par][wv][0] = make_float4(bv, __int_as_float(bi), ox, oy);
            slots[par][wv][4] = oz;
        }
        __syncthreads();  // one barrier per step; parity double-buffer
        float4 s0 = *(const float4*)&slots[par][0][0]; float z0 = slots[par][0][4];
        float4 s1 = *(const float4*)&slots[par][1][0]; float z1 = slots[par][1][4];
        float4 s2 = *(const float4*)&slots[par][2][0]; float z2 = slots[par][2][4];
        float4 s3 = *(const float4*)&slots[par][3][0]; float z3 = slots[par][3][4];
        float bval = s0.x; int bidx = __float_as_int(s0.y);
        cx = s0.z; cy = s0.w; cz = z0;
        {
            float vv = s1.x; int ii = __float_as_int(s1.y);
            bool bt = (vv > bval) || (vv == bval && ii < bidx);
            bval = bt ? vv : bval; bidx = bt ? ii : bidx;
            cx = bt ? s1.z : cx; cy = bt ? s1.w : cy; cz = bt ? z1 : cz;
        }
        {
            float vv = s2.x; int ii = __float_as_int(s2.y);
            bool bt = (vv > bval) || (vv == bval && ii < bidx);
            bval = bt ? vv : bval; bidx = bt ? ii : bidx;
            cx = bt ? s2.z : cx; cy = bt ? s2.w : cy; cz = bt ? z2 : cz;
        }
        {
            float vv = s3.x; int ii = __float_as_int(s3.y);
            bool bt = (vv > bval) || (vv == bval && ii < bidx);
            bval = bt ? vv : bval; bidx = bt ? ii : bidx;
            cx = bt ? s3.z : cx; cy = bt ? s3.w : cy; cz = bt ? z3 : cz;
        }
        par ^= 1;
    }
}

// ---------------- MFMA MLP layer ----------------
template <int MT, int KSTEPS, int NTW>
__device__ __forceinline__ void layer_mm(const unsigned short* A, const unsigned short* __restrict__ Wg,
                                         const float* __restrict__ bias, int lane, int wv,
                                         f4 (&acc)[MT][NTW])
{
    constexpr int KP = KSTEPS * 32;
    const int r15 = lane & 15, g = lane >> 4;
#pragma unroll
    for (int nt = 0; nt < NTW; ++nt) {
        int n = (wv * NTW + nt) * 16 + r15;
        float bv = bias[n];
#pragma unroll
        for (int mt = 0; mt < MT; ++mt) acc[mt][nt] = (f4){bv, bv, bv, bv};
    }
#pragma unroll
    for (int ks = 0; ks < KSTEPS; ++ks) {
        s8v afr[MT];
#pragma unroll
        for (int mt = 0; mt < MT; ++mt) {
            int row = mt * 16 + r15;
            int byte = ((row * KP + ks * 32 + g * 8) * 2) ^ ((row & 7) << 4);
            afr[mt] = *(const s8v*)((const char*)A + byte);
        }
#pragma unroll
        for (int nt = 0; nt < NTW; ++nt) {
            int n = (wv * NTW + nt) * 16 + r15;
            s8v bfr = *(const s8v*)(Wg + n * KP + ks * 32 + g * 8);
#pragma unroll
            for (int mt = 0; mt < MT; ++mt)
                acc[mt][nt] = __builtin_amdgcn_mfma_f32_16x16x32_bf16(afr[mt], bfr, acc[mt][nt], 0, 0, 0);
        }
    }
}

template <int MT, int NTW, int CO>
__device__ __forceinline__ void store_lds(f4 (&acc)[MT][NTW], unsigned short* OUT, int lane, int wv) {
    const int r15 = lane & 15, g = lane >> 4;
#pragma unroll
    for (int mt = 0; mt < MT; ++mt)
#pragma unroll
        for (int nt = 0; nt < NTW; ++nt)
#pragma unroll
            for (int q = 0; q < 4; ++q) {
                int j = mt * 16 + g * 4 + q;
                int n = (wv * NTW + nt) * 16 + r15;
                float v = fmaxf(acc[mt][nt][q], 0.f);
                int byte = ((j * CO + n) * 2) ^ ((j & 7) << 4);
                *(unsigned short*)((char*)OUT + byte) = f2bf(v);
            }
}

// ---------------- fused ball query + gather + MFMA MLP + max ----------------
template <int S_, int C1, int C2, int C3>
__device__ __forceinline__ void msg_body(int bm, char* smem,
    const float* __restrict__ pts, const unsigned short* __restrict__ ftr,
    const float* __restrict__ cent,
    const unsigned short* __restrict__ W0, const float* __restrict__ B0,
    const unsigned short* __restrict__ W1, const float* __restrict__ B1,
    const unsigned short* __restrict__ W2, const float* __restrict__ B2,
    float* __restrict__ outf, int ch_off, float rr)
{
    constexpr int MT = S_ / 16;
    constexpr int KS1 = C1 / 32, KS2 = C2 / 32;
    constexpr int NW1 = C1 / 64, NW2 = C2 / 64, NW3 = C3 / 64;
    constexpr int HA = (S_ * 96 > S_ * C2) ? S_ * 96 : S_ * C2;
    unsigned short* hA = (unsigned short*)smem;
    unsigned short* hB = hA + HA;
    int* nbr = (int*)(hB + S_ * C1);
    int* wtot = nbr + S_;
    const int tid = threadIdx.x, lane = tid & 63, wv = tid >> 6;
    const int b = bm >> 9, m = bm & (MCENT - 1);
    const float cx = cent[bm * 3], cy = cent[bm * 3 + 1], cz = cent[bm * 3 + 2];
    const float* px = pts + b * 3 * NPTS;
    const float* py = px + NPTS;
    const float* pz = py + NPTS;

    // ---- ball query: first S smallest in-ball indices (ascending) ----
    unsigned mask = 0; int cnt = 0;
    {
#pragma clang fp contract(off)
#pragma unroll
        for (int k = 0; k < 8; ++k) {
            int n = tid * 8 + k;
            float dx = cx - px[n], dy = cy - py[n], dz = cz - pz[n];
            float d2 = dx * dx + dy * dy;
            d2 = d2 + dz * dz;
            if (d2 <= rr) { mask |= 1u << k; ++cnt; }
        }
    }
    int inc = cnt;
#pragma unroll
    for (int off = 1; off < 64; off <<= 1) {
        int t = __shfl_up(inc, off);
        if (lane >= off) inc += t;
    }
    if (lane == 63) wtot[wv] = inc;
    __syncthreads();
    int base = 0, tot = 0;
#pragma unroll
    for (int w = 0; w < 4; ++w) { int t = wtot[w]; tot += t; if (w < wv) base += t; }
    int pos = base + inc - cnt;
#pragma unroll
    for (int k = 0; k < 8; ++k) {
        if ((mask >> k) & 1) {
            if (pos < S_) nbr[pos] = tid * 8 + k;
            ++pos;
        }
    }
    __syncthreads();
    const int first = nbr[0];

    // ---- gather: rows = [feat(64) ; rel_xyz(3) ; pad -> 96] bf16, swizzled ----
    for (int e = tid; e < S_ * 8; e += 256) {
        int j = e >> 3, c8 = e & 7;
        int p = (j < tot) ? nbr[j] : first;
        s8v v = *(const s8v*)(ftr + (b * NPTS + p) * 64 + c8 * 8);
        int byte = ((j * 96 + c8 * 8) * 2) ^ ((j & 7) << 4);
        *(s8v*)((char*)hA + byte) = v;
    }
    for (int e = tid; e < S_ * 4; e += 256) {
        int j = e >> 2, q = e & 3;
        int p = (j < tot) ? nbr[j] : first;
        s8v v = {0, 0, 0, 0, 0, 0, 0, 0};
        if (q == 0) {
            v[0] = (short)f2bf(px[p] - cx);
            v[1] = (short)f2bf(py[p] - cy);
            v[2] = (short)f2bf(pz[p] - cz);
        }
        int byte = ((j * 96 + 64 + q * 8) * 2) ^ ((j & 7) << 4);
        *(s8v*)((char*)hA + byte) = v;
    }
    __syncthreads();

    // ---- MLP: 3 MFMA layers ----
    {
        f4 acc[MT][NW1];
        layer_mm<MT, 3, NW1>(hA, W0, B0, lane, wv, acc);
        store_lds<MT, NW1, C1>(acc, hB, lane, wv);
    }
    __syncthreads();
    {
        f4 acc[MT][NW2];
        layer_mm<MT, KS1, NW2>(hB, W1, B1, lane, wv, acc);
        store_lds<MT, NW2, C2>(acc, hA, lane, wv);
    }
    __syncthreads();
    {
        f4 acc[MT][NW3];
        layer_mm<MT, KS2, NW3>(hA, W2, B2, lane, wv, acc);
        const int r15 = lane & 15;
        float* dst = outf + b * 384 * MCENT + ch_off * MCENT + m;
#pragma unroll
        for (int nt = 0; nt < NW3; ++nt) {
            float mv = -1e30f;
#pragma unroll
            for (int mt = 0; mt < MT; ++mt)
#pragma unroll
                for (int q = 0; q < 4; ++q) mv = fmaxf(mv, acc[mt][nt][q]);
            mv = fmaxf(mv, __shfl_xor(mv, 16));
            mv = fmaxf(mv, __shfl_xor(mv, 32));
            float v = fmaxf(mv, 0.f);
            if (lane < 16) dst[((wv * NW3 + nt) * 16 + r15) * MCENT] = v;
        }
    }
}

__global__ __launch_bounds__(256) void msg_both(
    const float* __restrict__ pts, const unsigned short* __restrict__ ftr,
    const float* __restrict__ cent, const unsigned short* __restrict__ wp,
    const float* __restrict__ b00, const float* __restrict__ b01, const float* __restrict__ b02,
    const float* __restrict__ b10, const float* __restrict__ b11, const float* __restrict__ b12,
    float* __restrict__ outf, float rr0, float rr1)
{
    extern __shared__ __align__(16) char smem[];
    if (blockIdx.x < BATCH * MCENT)
        msg_body<32, 64, 64, 128>(blockIdx.x, smem, pts, ftr, cent,
                                  wp + 0, b00, wp + 6144, b01, wp + 10240, b02, outf, 0, rr0);
    else
        msg_body<64, 128, 128, 256>(blockIdx.x - BATCH * MCENT, smem, pts, ftr, cent,
                                    wp + 18432, b10, wp + 30720, b11, wp + 47104, b12, outf, 128, rr1);
}

extern "C" void kernel_launch(void* const* d_in, const int* in_sizes, int n_in,
                              void* d_out, int out_size, void* d_ws, size_t ws_size,
                              hipStream_t stream) {
    const float* pts  = (const float*)d_in[0];
    const float* feats = (const float*)d_in[1];
    const float* w00 = (const float*)d_in[2];  const float* b00 = (const float*)d_in[3];
    const float* w01 = (const float*)d_in[4];  const float* b01 = (const float*)d_in[5];
    const float* w02 = (const float*)d_in[6];  const float* b02 = (const float*)d_in[7];
    const float* w10 = (const float*)d_in[8];  const float* b10 = (const float*)d_in[9];
    const float* w11 = (const float*)d_in[10]; const float* b11 = (const float*)d_in[11];
    const float* w12 = (const float*)d_in[12]; const float* b12 = (const float*)d_in[13];
    float* out = (float*)d_out;
    char* ws = (char*)d_ws;
    float* cent = (float*)ws;                                       // 24576 B
    unsigned short* ftr = (unsigned short*)(ws + 24576);            // 1048576 B
    unsigned short* wp  = (unsigned short*)(ws + 24576 + 1048576);  // 159744 B

    hipLaunchKernelGGL(fps_prep, dim3(68), dim3(256), 0, stream,
                       pts, feats, w00, w01, w02, w10, w11, w12, cent, ftr, wp, out);
    float* outf = out + BATCH * 3 * MCENT;
    const float RR0 = (float)(0.2 * 0.2);
    const float RR1 = (float)(0.4 * 0.4);
    hipLaunchKernelGGL(msg_both, dim3(2 * BATCH * MCENT), dim3(256), 33040, stream,
                       pts, ftr, cent, wp, b00, b01, b02, b10, b11, b12, outf, RR0, RR1);
}